// Round 10
// baseline (60.364 us; speedup 1.0000x reference)
//
#include <hip/hip_runtime.h>
#include <cstddef>

// Problem constants
#define NB 4
#define LQ 512
#define LK 512
#define QF 256
#define NH 128
#define VD 256

__device__ __forceinline__ float fexp2(float x) {
    float r; asm("v_exp_f32 %0, %1" : "=v"(r) : "v"(x)); return r;
}
__device__ __forceinline__ float frcp(float x) {
    float r; asm("v_rcp_f32 %0, %1" : "=v"(r) : "v"(x)); return r;
}
__device__ __forceinline__ void fma4(float4& acc, float s, const float4 v) {
    acc.x = __builtin_fmaf(s, v.x, acc.x);
    acc.y = __builtin_fmaf(s, v.y, acc.y);
    acc.z = __builtin_fmaf(s, v.z, acc.z);
    acc.w = __builtin_fmaf(s, v.w, acc.w);
}

constexpr float kLog2e    = 1.4426950408889634f;
constexpr float kPreScale = 2.0f * kLog2e;   // tanh(x) = 1 - 2/(1 + exp2(kPreScale*x))

// ---------------------------------------------------------------------------
// K0: transpose W_q, W_k into f4-major float4 tiles (FROZEN).
// ---------------------------------------------------------------------------
__global__ __launch_bounds__(256) void transw_kernel(
    const float* __restrict__ W_q, const float* __restrict__ W_k,
    float4* __restrict__ wt)
{
    const int bid = blockIdx.x;          // 16 = 2 mats * 8 f4-groups
    const int mat = bid & 1;
    const int f4b = (bid >> 1) * 8;
    const float4* W4 = (const float4*)(mat ? W_k : W_q);
    float4* o = wt + (size_t)mat * 64 * NH;

    const int t  = threadIdx.x;
    const int h  = t & 127;
    const int fo = t >> 7;
    #pragma unroll
    for (int it = 0; it < 4; ++it) {
        const int f4 = f4b + fo + 2 * it;
        o[f4 * NH + h] = W4[h * 64 + f4];
    }
}

// ---------------------------------------------------------------------------
// K1: projections + exponentials (FROZEN).
//   eq  [row][h]             = exp2(ps * Q.Wq^T)   [2048][128]
//   ekt4[b][h4][j][c] (f32)  = exp2(ps * K.Wk^T), h=4*h4+c
// ---------------------------------------------------------------------------
__global__ __launch_bounds__(256) void proj_kernel(
    const float* __restrict__ queries, const float* __restrict__ keys,
    const float4* __restrict__ wt,
    float* __restrict__ eq, float* __restrict__ ekt4f)
{
    const int bid   = blockIdx.x;        // 512 = 2 which * 256 row-tiles(8)
    const int which = bid & 1;
    const int rt    = bid >> 1;
    const int row0  = rt * 8;
    const float4* In4 = (const float4*)(which ? keys : queries);
    const float4* w4  = wt + (size_t)which * 64 * NH;

    __shared__ float4 rows[8][64];       // 8KB

    const int t    = threadIdx.x;
    const int lane = t & 63;
    const int wid  = t >> 6;

    {   // stage 8 rows, coalesced
        const int f4 = t & 63;
        const int r  = t >> 6;
        rows[r][f4]     = In4[(size_t)(row0 + r) * 64 + f4];
        rows[r + 4][f4] = In4[(size_t)(row0 + r + 4) * 64 + f4];
    }
    __syncthreads();

    const int r0 = wid * 2;              // wave's 2 rows
    float acc[2][2] = {};
    #pragma unroll 4
    for (int f4 = 0; f4 < 64; ++f4) {
        const float4 w0 = w4[f4 * NH + lane];        // coalesced 1KB
        const float4 w1 = w4[f4 * NH + lane + 64];
        #pragma unroll
        for (int r = 0; r < 2; ++r) {
            const float4 x = rows[r0 + r][f4];       // wave-uniform broadcast
            acc[r][0] += w0.x * x.x + w0.y * x.y + w0.z * x.z + w0.w * x.w;
            acc[r][1] += w1.x * x.x + w1.y * x.y + w1.z * x.z + w1.w * x.w;
        }
    }

    if (which == 0) {
        #pragma unroll
        for (int r = 0; r < 2; ++r) {
            const size_t o = (size_t)(row0 + r0 + r) * NH;
            eq[o + lane]      = fexp2(kPreScale * acc[r][0]);
            eq[o + lane + 64] = fexp2(kPreScale * acc[r][1]);
        }
    } else {
        const int b  = row0 >> 9;
        const int j0 = (row0 & 511) + r0;
        #pragma unroll
        for (int r = 0; r < 2; ++r) {
            #pragma unroll
            for (int s = 0; s < 2; ++s) {
                const int h = lane + 64 * s;
                ekt4f[(((size_t)b * 32 + (h >> 2)) * LK + j0 + r) * 4 + (h & 3)]
                    = fexp2(kPreScale * acc[r][s]);
            }
        }
    }
}

// ---------------------------------------------------------------------------
// K2 (FUSED, reuse-tiled): block = (b, 8-query tile, FULL 512 j).
// 256 blocks x 512 thr (8 waves); uniform full-LK cost -> lockstep finish.
//
// Phase S: wave (qg = w&1, jg = w>>2... see below) holds 4 queries x 2
//   j-points: each Ek float4 load is reused by 8 accumulator chains (R9
//   loaded it once per single query -> 537 MB of L2 traffic; now ~130 MB).
//   q read from LDS as uniform b128 broadcasts (4 per h4 per wave).
// Norm: per-wave shfl reduce -> reds[8][4] -> rs per query.
// attn written to GLOBAL (coalesced), __syncthreads (drains vmem), then
// Phase PV re-reads attn per-j as wave-uniform scalar loads (constant
//   cache) + 1KB coalesced values load + 32 fma; per-wave partials through
//   pacc[8][8][64] (64 KB), two-round-free 8-way final reduce.
// ---------------------------------------------------------------------------
__global__ __launch_bounds__(512, 2) void fused_kernel(
    const float* __restrict__ eq, const float* __restrict__ ekt4f,
    const float* __restrict__ values, const int* __restrict__ valid_lens,
    const float* __restrict__ W_v,
    float* __restrict__ out, float* __restrict__ attn_out)
{
    const int id = blockIdx.x;           // 256 = 64 qt * 4 b (b fastest)
    const int b  = id & 3;
    const int i0 = (id >> 2) * 8;
    const int vl = valid_lens[b];

    __shared__ float  eq_lds[8][NH];     // 4KB
    __shared__ float  wv[NH];            // 512B
    __shared__ float  reds[8][4];
    __shared__ float4 pacc[8][8][64];    // 64KB

    const int t    = threadIdx.x;        // 0..511
    const int wid  = t >> 6;
    const int lane = t & 63;
    const int qg   = wid & 1;            // query group (4 q each)
    const int jg   = wid >> 1;           // j group (128 j each)
    const int q0   = qg * 4;

    {   // stage 8 eq rows (1024 floats) + wv
        const float* qrow = eq + (size_t)(b * LQ + i0) * NH;
        ((float*)eq_lds)[t]       = qrow[t];
        ((float*)eq_lds)[t + 512] = qrow[t + 512];
        if (t < NH) wv[t] = W_v[t];
    }
    __syncthreads();

    const float4* wv4 = (const float4*)wv;
    float sumA = 0.f, sumW = 0.f;
    #pragma unroll 8
    for (int h4 = 0; h4 < NH / 4; ++h4) {
        const float4 w = wv4[h4];
        sumW += (w.x + w.y) + (w.z + w.w);
        sumA += (fabsf(w.x) + fabsf(w.y)) + (fabsf(w.z) + fabsf(w.w));
    }

    // ---- Phase S: 4 queries x 2 j-points per wave, full LK ----
    const int j0 = jg * 128 + lane;
    const int j1 = j0 + 64;
    const float4* ek = (const float4*)ekt4f + (size_t)b * 32 * LK;

    float acc[4][2] = {};
    #pragma unroll 2
    for (int h4 = 0; h4 < NH / 4; ++h4) {
        const float4 e0 = ek[(size_t)h4 * LK + j0];  // 16B/lane, reused 8x
        const float4 e1 = ek[(size_t)h4 * LK + j1];
        const float4 w  = wv4[h4];
        #pragma unroll
        for (int qq = 0; qq < 4; ++qq) {
            const float4 qv = *(const float4*)&eq_lds[q0 + qq][h4 * 4]; // uniform
            float r;
            r = frcp(__builtin_fmaf(qv.x, e0.x, 1.f)); acc[qq][0] = __builtin_fmaf(w.x, r, acc[qq][0]);
            r = frcp(__builtin_fmaf(qv.y, e0.y, 1.f)); acc[qq][0] = __builtin_fmaf(w.y, r, acc[qq][0]);
            r = frcp(__builtin_fmaf(qv.z, e0.z, 1.f)); acc[qq][0] = __builtin_fmaf(w.z, r, acc[qq][0]);
            r = frcp(__builtin_fmaf(qv.w, e0.w, 1.f)); acc[qq][0] = __builtin_fmaf(w.w, r, acc[qq][0]);
            r = frcp(__builtin_fmaf(qv.x, e1.x, 1.f)); acc[qq][1] = __builtin_fmaf(w.x, r, acc[qq][1]);
            r = frcp(__builtin_fmaf(qv.y, e1.y, 1.f)); acc[qq][1] = __builtin_fmaf(w.y, r, acc[qq][1]);
            r = frcp(__builtin_fmaf(qv.z, e1.z, 1.f)); acc[qq][1] = __builtin_fmaf(w.z, r, acc[qq][1]);
            r = frcp(__builtin_fmaf(qv.w, e1.w, 1.f)); acc[qq][1] = __builtin_fmaf(w.w, r, acc[qq][1]);
        }
    }

    // p = exp(s - M); mask j >= vl AFTER compute (uniform cost)
    float p[4][2];
    #pragma unroll
    for (int qq = 0; qq < 4; ++qq) {
        #pragma unroll
        for (int u = 0; u < 2; ++u) {
            const float s = __builtin_fmaf(-2.f, acc[qq][u], sumW);
            float pv = fexp2((s - sumA) * kLog2e);
            if ((u ? j1 : j0) >= vl) pv = 0.f;
            p[qq][u] = pv;
        }
    }

    // ---- per-query sum: shfl within wave, LDS across jg waves ----
    #pragma unroll
    for (int qq = 0; qq < 4; ++qq) {
        float s = p[qq][0] + p[qq][1];
        #pragma unroll
        for (int off = 1; off < 64; off <<= 1)
            s += __shfl_xor(s, off, 64);
        if (lane == 0) reds[wid][qq] = s;
    }
    __syncthreads();

    float rs[4];
    #pragma unroll
    for (int qq = 0; qq < 4; ++qq)
        rs[qq] = frcp((reds[qg][qq]     + reds[qg + 2][qq]) +
                      (reds[qg + 4][qq] + reds[qg + 6][qq]));

    float* abase = attn_out + (size_t)(b * LQ + i0) * LK;
    #pragma unroll
    for (int qq = 0; qq < 4; ++qq) {
        float* arow = abase + (size_t)(q0 + qq) * LK;
        arow[j0] = p[qq][0] * rs[qq];    // coalesced 256B
        arow[j1] = p[qq][1] * rs[qq];
    }
    __syncthreads();                     // drains vmem: attn visible to block

    // ---- Phase PV: wave w owns j-strip [64w, 64w+64), lane = col-quad ----
    float4 oacc[8];
    #pragma unroll
    for (int q = 0; q < 8; ++q) oacc[q] = float4{0.f, 0.f, 0.f, 0.f};

    const float4* v4 = (const float4*)(values + (size_t)b * LK * VD);
    const int js = wid * 64;
    #pragma unroll 2
    for (int j = js; j < js + 64; ++j) {
        const float4 vv = v4[(size_t)j * 64 + lane];       // coalesced 1KB
        #pragma unroll
        for (int q = 0; q < 8; ++q) {
            const float aq = abase[(size_t)q * LK + j];    // wave-uniform (s_load)
            fma4(oacc[q], aq, vv);
        }
    }

    #pragma unroll
    for (int q = 0; q < 8; ++q) pacc[wid][q][lane] = oacc[q];
    __syncthreads();

    {   // final reduce: thread -> (q = t>>6, col-quad c4 = t&63)
        const int q  = t >> 6;
        const int c4 = t & 63;
        float4 s = pacc[0][q][c4];
        #pragma unroll
        for (int k = 1; k < 8; ++k) {
            const float4 v = pacc[k][q][c4];
            s.x += v.x; s.y += v.y; s.z += v.z; s.w += v.w;
        }
        ((float4*)(out + (size_t)(b * LQ + i0 + q) * VD))[c4] = s;
    }
}

// ---------------------------------------------------------------------------
extern "C" void kernel_launch(void* const* d_in, const int* in_sizes, int n_in,
                              void* d_out, int out_size, void* d_ws, size_t ws_size,
                              hipStream_t stream)
{
    const float* queries    = (const float*)d_in[0];
    const float* keys       = (const float*)d_in[1];
    const float* values     = (const float*)d_in[2];
    const int*   valid_lens = (const int*)  d_in[3];
    const float* W_q        = (const float*)d_in[4];
    const float* W_k        = (const float*)d_in[5];
    const float* W_v        = (const float*)d_in[6];

    float* out      = (float*)d_out;                       // [NB, LQ, VD]
    float* attn_out = out + (size_t)NB * LQ * VD;          // [NB, LQ, LK]

    float*  eq    = (float*)d_ws;                          // [2048][128]  1MB
    float*  ekt4f = eq + (size_t)NB * LQ * NH;             // [4][32][512][4] 1MB
    float4* wt    = (float4*)(ekt4f + (size_t)NB * NH * LK); // [2][64][128] 256KB

    transw_kernel<<<16,  256, 0, stream>>>(W_q, W_k, wt);
    proj_kernel  <<<512, 256, 0, stream>>>(queries, keys, wt, eq, ekt4f);
    fused_kernel <<<256, 512, 0, stream>>>(eq, ekt4f, values, valid_lens, W_v,
                                           out, attn_out);
}

// Round 11
// 49.588 us; speedup vs baseline: 1.2173x; 1.2173x over previous
//
#include <hip/hip_runtime.h>
#include <cstddef>

// Problem constants
#define NB 4
#define LQ 512
#define LK 512
#define QF 256
#define NH 128
#define VD 256

__device__ __forceinline__ float fexp2(float x) {
    float r; asm("v_exp_f32 %0, %1" : "=v"(r) : "v"(x)); return r;
}
__device__ __forceinline__ float frcp(float x) {
    float r; asm("v_rcp_f32 %0, %1" : "=v"(r) : "v"(x)); return r;
}
__device__ __forceinline__ void fma4(float4& acc, float s, const float4 v) {
    acc.x = __builtin_fmaf(s, v.x, acc.x);
    acc.y = __builtin_fmaf(s, v.y, acc.y);
    acc.z = __builtin_fmaf(s, v.z, acc.z);
    acc.w = __builtin_fmaf(s, v.w, acc.w);
}

constexpr float kLog2e    = 1.4426950408889634f;
constexpr float kPreScale = 2.0f * kLog2e;   // tanh(x) = 1 - 2/(1 + exp2(kPreScale*x))

// ---------------------------------------------------------------------------
// K0: transpose W_q, W_k into f4-major float4 tiles (FROZEN).
// ---------------------------------------------------------------------------
__global__ __launch_bounds__(256) void transw_kernel(
    const float* __restrict__ W_q, const float* __restrict__ W_k,
    float4* __restrict__ wt)
{
    const int bid = blockIdx.x;          // 16 = 2 mats * 8 f4-groups
    const int mat = bid & 1;
    const int f4b = (bid >> 1) * 8;
    const float4* W4 = (const float4*)(mat ? W_k : W_q);
    float4* o = wt + (size_t)mat * 64 * NH;

    const int t  = threadIdx.x;
    const int h  = t & 127;
    const int fo = t >> 7;
    #pragma unroll
    for (int it = 0; it < 4; ++it) {
        const int f4 = f4b + fo + 2 * it;
        o[f4 * NH + h] = W4[h * 64 + f4];
    }
}

// ---------------------------------------------------------------------------
// K1: projections + exponentials (FROZEN).
//   eq  [row][h]             = exp2(ps * Q.Wq^T)   [2048][128]
//   ekt4[b][h4][j][c] (f32)  = exp2(ps * K.Wk^T), h=4*h4+c
// ---------------------------------------------------------------------------
__global__ __launch_bounds__(256) void proj_kernel(
    const float* __restrict__ queries, const float* __restrict__ keys,
    const float4* __restrict__ wt,
    float* __restrict__ eq, float* __restrict__ ekt4f)
{
    const int bid   = blockIdx.x;        // 512 = 2 which * 256 row-tiles(8)
    const int which = bid & 1;
    const int rt    = bid >> 1;
    const int row0  = rt * 8;
    const float4* In4 = (const float4*)(which ? keys : queries);
    const float4* w4  = wt + (size_t)which * 64 * NH;

    __shared__ float4 rows[8][64];       // 8KB

    const int t    = threadIdx.x;
    const int lane = t & 63;
    const int wid  = t >> 6;

    {   // stage 8 rows, coalesced
        const int f4 = t & 63;
        const int r  = t >> 6;
        rows[r][f4]     = In4[(size_t)(row0 + r) * 64 + f4];
        rows[r + 4][f4] = In4[(size_t)(row0 + r + 4) * 64 + f4];
    }
    __syncthreads();

    const int r0 = wid * 2;              // wave's 2 rows
    float acc[2][2] = {};
    #pragma unroll 4
    for (int f4 = 0; f4 < 64; ++f4) {
        const float4 w0 = w4[f4 * NH + lane];        // coalesced 1KB
        const float4 w1 = w4[f4 * NH + lane + 64];
        #pragma unroll
        for (int r = 0; r < 2; ++r) {
            const float4 x = rows[r0 + r][f4];       // wave-uniform broadcast
            acc[r][0] += w0.x * x.x + w0.y * x.y + w0.z * x.z + w0.w * x.w;
            acc[r][1] += w1.x * x.x + w1.y * x.y + w1.z * x.z + w1.w * x.w;
        }
    }

    if (which == 0) {
        #pragma unroll
        for (int r = 0; r < 2; ++r) {
            const size_t o = (size_t)(row0 + r0 + r) * NH;
            eq[o + lane]      = fexp2(kPreScale * acc[r][0]);
            eq[o + lane + 64] = fexp2(kPreScale * acc[r][1]);
        }
    } else {
        const int b  = row0 >> 9;
        const int j0 = (row0 & 511) + r0;
        #pragma unroll
        for (int r = 0; r < 2; ++r) {
            #pragma unroll
            for (int s = 0; s < 2; ++s) {
                const int h = lane + 64 * s;
                ekt4f[(((size_t)b * 32 + (h >> 2)) * LK + j0 + r) * 4 + (h & 3)]
                    = fexp2(kPreScale * acc[r][s]);
            }
        }
    }
}

// ---------------------------------------------------------------------------
// K2 (FUSED, TQ=2, batch-spanning grid): R8's proven inner math, reshaped.
// Grid 1024 = b*256 + qt  (b in HIGH bits): under round-robin placement
// CU c hosts blocks {c, c+256, c+512, c+768} -> ALL 4 batches -> per-CU work
// = sum_b vl_b = uniform by construction (R8's b=id&3 gave every CU a single
// batch -> occupancy 47%).  4 assigned vs 2 resident blocks/CU -> backfill.
// 1024 thr = 16 waves: wave w = (query qi = w&1, chunk g = w>>1); one 64-j
// chunk per wave, vl-masked compute, unconditional attn write (zeros).
// PV: wave w -> j-strip [32w, min(32w+32, vl)); two-round pacc reduce.
// LDS ~22.5 KB.
// ---------------------------------------------------------------------------
__global__ __launch_bounds__(1024, 8) void fused_kernel(
    const float* __restrict__ eq, const float* __restrict__ ekt4f,
    const float* __restrict__ values, const int* __restrict__ valid_lens,
    const float* __restrict__ W_v,
    float* __restrict__ out, float* __restrict__ attn_out)
{
    const int id = blockIdx.x;           // 1024 = 4 b * 256 qt (b HIGH)
    const int b  = id >> 8;
    const int i0 = (id & 255) * 2;
    const int vl = valid_lens[b];

    __shared__ float  eq_lds[2][NH];     // 1KB
    __shared__ float  wv[NH];            // 512B
    __shared__ float  attn_t[LK][2];     // 4KB [j][q]
    __shared__ float4 pacc[8][2][VD / 4];// 16KB
    __shared__ float  reds[16];

    const int t    = threadIdx.x;
    const int wid  = t >> 6;
    const int lane = t & 63;
    const int qi   = wid & 1;
    const int g    = wid >> 1;           // chunk 0..7

    if (t < 2 * NH) ((float*)eq_lds)[t] = eq[(size_t)(b * LQ + i0) * NH + t];
    if (t < NH)     wv[t] = W_v[t];
    __syncthreads();

    const float4* q4  = (const float4*)eq_lds[qi];
    const float4* wv4 = (const float4*)wv;

    float sumA = 0.f, sumW = 0.f;
    #pragma unroll 8
    for (int h4 = 0; h4 < NH / 4; ++h4) {
        const float4 w = wv4[h4];
        sumW += (w.x + w.y) + (w.z + w.w);
        sumA += (fabsf(w.x) + fabsf(w.y)) + (fabsf(w.z) + fabsf(w.w));
    }

    // ---- Phase S: wave's single chunk g of query qi (vl-masked) ----
    const int j = g * 64 + lane;
    float pv = 0.f;
    if (g * 64 < vl) {                   // wave-uniform skip
        const float4* pk4 = (const float4*)ekt4f + (size_t)b * 32 * LK + j;
        float a0 = 0.f, a1 = 0.f, a2 = 0.f, a3 = 0.f;
        #pragma unroll 4
        for (int h4 = 0; h4 < NH / 4; ++h4) {
            const float4 e = pk4[(size_t)h4 * LK];   // 16B/lane, 1KB/wave
            const float4 w = wv4[h4];
            const float4 q = q4[h4];
            a0 = __builtin_fmaf(w.x, frcp(__builtin_fmaf(q.x, e.x, 1.f)), a0);
            a1 = __builtin_fmaf(w.y, frcp(__builtin_fmaf(q.y, e.y, 1.f)), a1);
            a2 = __builtin_fmaf(w.z, frcp(__builtin_fmaf(q.z, e.z, 1.f)), a2);
            a3 = __builtin_fmaf(w.w, frcp(__builtin_fmaf(q.w, e.w, 1.f)), a3);
        }
        const float s = __builtin_fmaf(-2.f, (a0 + a1) + (a2 + a3), sumW);
        pv = fexp2((s - sumA) * kLog2e);
        if (j >= vl) pv = 0.f;           // tail of boundary chunk
    }

    // ---- per-query sum across 8 g-waves ----
    float sum = pv;
    #pragma unroll
    for (int off = 1; off < 64; off <<= 1)
        sum += __shfl_xor(sum, off, 64);
    if (lane == 0) reds[wid] = sum;
    __syncthreads();
    float rsum = 0.f;
    #pragma unroll
    for (int k = 0; k < 8; ++k) rsum += reds[qi + 2 * k];
    const float rs = frcp(rsum);

    {   // attn write: global (coalesced) + LDS, unconditional (zeros beyond vl)
        const float a = pv * rs;
        attn_out[(size_t)(b * LQ + i0 + qi) * LK + j] = a;
        attn_t[j][qi] = a;
    }
    __syncthreads();

    // ---- Phase PV: wave w -> j-strip [32w, min(32w+32, vl)) ----
    float4 oacc[2] = {float4{0.f,0.f,0.f,0.f}, float4{0.f,0.f,0.f,0.f}};
    const int j0 = wid * 32;
    const int j1 = min(j0 + 32, vl);
    const float4* v4 = (const float4*)(values + (size_t)b * LK * VD);
    for (int jj = j0; jj < j1; ++jj) {
        const float2 a2 = *(const float2*)&attn_t[jj][0];  // both q (uniform)
        const float4 vv = v4[(size_t)jj * 64 + lane];      // coalesced 1KB
        fma4(oacc[0], a2.x, vv);
        fma4(oacc[1], a2.y, vv);
    }

    if (wid < 8) {
        pacc[wid][0][lane] = oacc[0];
        pacc[wid][1][lane] = oacc[1];
    }
    __syncthreads();
    if (wid >= 8) {
        #pragma unroll
        for (int q = 0; q < 2; ++q) {
            const float4 p0 = pacc[wid - 8][q][lane];
            pacc[wid - 8][q][lane] =
                float4{p0.x + oacc[q].x, p0.y + oacc[q].y,
                       p0.z + oacc[q].z, p0.w + oacc[q].w};
        }
    }
    __syncthreads();

    if (t < 512) {                       // out: (q = t>>8, c = t&255)
        const int q = t >> 8;
        const int c = t & 255;
        float s = 0.f;
        #pragma unroll
        for (int k = 0; k < 8; ++k)
            s += ((const float*)&pacc[k][q][0])[c];
        out[(size_t)(b * LQ + i0 + q) * VD + c] = s;
    }
}

// ---------------------------------------------------------------------------
extern "C" void kernel_launch(void* const* d_in, const int* in_sizes, int n_in,
                              void* d_out, int out_size, void* d_ws, size_t ws_size,
                              hipStream_t stream)
{
    const float* queries    = (const float*)d_in[0];
    const float* keys       = (const float*)d_in[1];
    const float* values     = (const float*)d_in[2];
    const int*   valid_lens = (const int*)  d_in[3];
    const float* W_q        = (const float*)d_in[4];
    const float* W_k        = (const float*)d_in[5];
    const float* W_v        = (const float*)d_in[6];

    float* out      = (float*)d_out;                       // [NB, LQ, VD]
    float* attn_out = out + (size_t)NB * LQ * VD;          // [NB, LQ, LK]

    float*  eq    = (float*)d_ws;                          // [2048][128]  1MB
    float*  ekt4f = eq + (size_t)NB * LQ * NH;             // [4][32][512][4] 1MB
    float4* wt    = (float4*)(ekt4f + (size_t)NB * NH * LK); // [2][64][128] 256KB

    transw_kernel<<<16,   256,  0, stream>>>(W_q, W_k, wt);
    proj_kernel  <<<512,  256,  0, stream>>>(queries, keys, wt, eq, ekt4f);
    fused_kernel <<<1024, 1024, 0, stream>>>(eq, ekt4f, values, valid_lens, W_v,
                                             out, attn_out);
}